// Round 3
// baseline (179.733 us; speedup 1.0000x reference)
//
#include <hip/hip_runtime.h>

// HitTheMiddleModel: per-row physics sim + 1e-10 * tiny linear.
// R3: LDS-staged layout transform.
//   - Stage: 3 coalesced global_load_dwordx4 per thread into LDS (768 float4
//     per 256-thread block = 1024 rows). One load per float4, no overlap.
//   - Compute: thread t handles rows {t, t+256, t+512, t+768} (block-local).
//     LDS float reads at index 3*lr+c -> bank (3*lr+c)%32 -> 2-way aliasing
//     across 64 lanes = conflict-free (m136). Branch-free sim. Results
//     written back IN PLACE (same row slots, same thread -> no race, no
//     second buffer, no extra barrier).
//   - Store: 3 coalesced global_store_dwordx4 per thread.
// R2 post-mortem: per-lane q%3 phase branch made every wave run all 3 paths
// at 1/3 utilization, and each float4 was loaded 3x. Kernel sat at ~2.7 TB/s
// vs fill's 6.6. This version is structurally a float4 copy + LDS transform.

#define BLOCK 256
#define R_PER_T 4
#define ROWS_PER_BLOCK (BLOCK * R_PER_T)        // 1024 rows
#define F4_PER_BLOCK (ROWS_PER_BLOCK * 3 / 4)   // 768 float4 = 12 KiB

__device__ __forceinline__ void sim_row(float x0, float x1, float x2,
                                        const float* Wv, const float* bv,
                                        float& pos_o, float& vel_o, float& rew_o) {
    float vel = x1 + x2;
    float pos = x0 + vel;
    bool hit = (pos > 10.0f) || (pos < -10.0f);
    vel = hit ? -vel : vel;
    pos = fminf(10.0f, fmaxf(-10.0f, pos));
    float reward = -pos * pos;
    // y = x @ W^T + b  (W row-major [3,3]); weighted 1e-10 in the output.
    float y0 = fmaf(x0, Wv[0], fmaf(x1, Wv[1], fmaf(x2, Wv[2], bv[0])));
    float y1 = fmaf(x0, Wv[3], fmaf(x1, Wv[4], fmaf(x2, Wv[5], bv[1])));
    float y2 = fmaf(x0, Wv[6], fmaf(x1, Wv[7], fmaf(x2, Wv[8], bv[2])));
    pos_o = fmaf(1e-10f, y0, pos);
    vel_o = fmaf(1e-10f, y1, vel);
    rew_o = fmaf(1e-10f, y2, reward);
}

__global__ __launch_bounds__(BLOCK) void HitTheMiddleModel_kernel(
        const float4* __restrict__ X4,
        const float* __restrict__ W,
        const float* __restrict__ B,
        float4* __restrict__ O4,
        long long n4, long long safeRows) {
    __shared__ float4 lds4[F4_PER_BLOCK];
    float* ldsf = (float*)lds4;

    const int t = threadIdx.x;
    const long long f4base = (long long)blockIdx.x * F4_PER_BLOCK;
    const long long rowbase = (long long)blockIdx.x * ROWS_PER_BLOCK;

    // Wave-uniform -> scalar loads, cached.
    float Wv[9];
#pragma unroll
    for (int i = 0; i < 9; ++i) Wv[i] = W[i];
    float bv[3] = {B[0], B[1], B[2]};

    // ---- Stage: global -> LDS, fully coalesced, one touch per float4 ----
#pragma unroll
    for (int k = 0; k < 3; ++k) {
        long long g = f4base + t + k * BLOCK;
        if (g < n4) lds4[t + k * BLOCK] = X4[g];
    }
    __syncthreads();

    // ---- Compute: 4 whole rows per thread, branch-free, in-place ----
#pragma unroll
    for (int k = 0; k < R_PER_T; ++k) {
        int lr = t + k * BLOCK;                 // block-local row
        long long row = rowbase + lr;
        if (row < safeRows) {
            float x0 = ldsf[3 * lr + 0];
            float x1 = ldsf[3 * lr + 1];
            float x2 = ldsf[3 * lr + 2];
            float p, v, rw;
            sim_row(x0, x1, x2, Wv, bv, p, v, rw);
            ldsf[3 * lr + 0] = p;
            ldsf[3 * lr + 1] = v;
            ldsf[3 * lr + 2] = rw;
        }
    }
    __syncthreads();

    // ---- Store: LDS -> global, fully coalesced ----
#pragma unroll
    for (int k = 0; k < 3; ++k) {
        long long g = f4base + t + k * BLOCK;
        if (g < n4) O4[g] = lds4[t + k * BLOCK];
    }
}

// Scalar tail for rows whose floats extend past 4*n4 (only if nfloats%4 != 0;
// never launched for B = 2^23 where nfloats = 3*B is divisible by 4).
__global__ void HitTheMiddleModel_tail(
        const float* __restrict__ X, const float* __restrict__ W,
        const float* __restrict__ B, float* __restrict__ O,
        long long startFloat, long long nfloats) {
    long long g = startFloat + blockIdx.x * blockDim.x + threadIdx.x;
    if (g >= nfloats) return;
    float Wv[9];
    for (int i = 0; i < 9; ++i) Wv[i] = W[i];
    float bv[3] = {B[0], B[1], B[2]};
    long long row = g / 3;
    int c = (int)(g % 3);
    float x0 = X[3 * row], x1 = X[3 * row + 1], x2 = X[3 * row + 2];
    float p, v, rw;
    sim_row(x0, x1, x2, Wv, bv, p, v, rw);
    O[g] = (c == 0) ? p : (c == 1) ? v : rw;
}

extern "C" void kernel_launch(void* const* d_in, const int* in_sizes, int n_in,
                              void* d_out, int out_size, void* d_ws, size_t ws_size,
                              hipStream_t stream) {
    const float* x = (const float*)d_in[0];
    const float* W = (const float*)d_in[1];
    const float* b = (const float*)d_in[2];
    float* out = (float*)d_out;

    long long nfloats = (long long)in_sizes[0];   // 3 * rows
    long long rows = nfloats / 3;
    long long n4 = nfloats / 4;                   // full float4s
    // Rows fully contained in the staged float4 region:
    long long safeRows = (4 * n4) / 3;
    if (safeRows > rows) safeRows = rows;

    long long grid = (rows + ROWS_PER_BLOCK - 1) / ROWS_PER_BLOCK;
    HitTheMiddleModel_kernel<<<(int)grid, BLOCK, 0, stream>>>(
        (const float4*)x, W, b, (float4*)out, n4, safeRows);

    long long startFloat = 3 * safeRows;          // first float not covered
    if (startFloat < nfloats) {
        long long tailN = nfloats - startFloat;
        int tgrid = (int)((tailN + 255) / 256);
        HitTheMiddleModel_tail<<<tgrid, 256, 0, stream>>>(
            x, W, b, out, startFloat, nfloats);
    }
}

// Round 5
// 173.961 us; speedup vs baseline: 1.0332x; 1.0332x over previous
//
#include <hip/hip_runtime.h>

// HitTheMiddleModel: per-row physics sim + 1e-10 * tiny linear.
// R5 = R4 with the right-halo address fixed (ra = 4q+4, was erroneously 4q+8).
//   Thread q owns output float4 O4[q]. Inputs needed are floats 4q-2..4q+5,
//   i.e. window w2..w9 where w-index i <-> global float 4q-4+i:
//     one b128 load X4[q]   -> w4..w7  (floats 4q..4q+3)
//     8 B halo at 4q-2      -> w2,w3
//     8 B halo at 4q+4      -> w8,w9
//   Halo overlap served by L1. Phase m = q%3 handled by cndmask selects (no
//   divergence). No LDS, no barriers, all wave mem-ops lane-contiguous.
// Clamp safety: q==0 -> phase 0, w2/w3 unused; last q (n4=3*2^21) -> phase 2,
//   w8/w9 unused. Clamped junk is never consumed.

__device__ __forceinline__ void sim_row(float x0, float x1, float x2,
                                        const float* Wv, const float* bv,
                                        float& pos_o, float& vel_o, float& rew_o) {
    float vel = x1 + x2;
    float pos = x0 + vel;
    bool hit = (pos > 10.0f) || (pos < -10.0f);
    vel = hit ? -vel : vel;
    pos = fminf(10.0f, fmaxf(-10.0f, pos));
    float reward = -pos * pos;
    float y0 = fmaf(x0, Wv[0], fmaf(x1, Wv[1], fmaf(x2, Wv[2], bv[0])));
    float y1 = fmaf(x0, Wv[3], fmaf(x1, Wv[4], fmaf(x2, Wv[5], bv[1])));
    float y2 = fmaf(x0, Wv[6], fmaf(x1, Wv[7], fmaf(x2, Wv[8], bv[2])));
    pos_o = fmaf(1e-10f, y0, pos);
    vel_o = fmaf(1e-10f, y1, vel);
    rew_o = fmaf(1e-10f, y2, reward);
}

// 3-way select, branch-free (2 cndmask).
__device__ __forceinline__ float sel3(int m, float a, float b, float c) {
    float r = (m == 1) ? b : c;
    return (m == 0) ? a : r;
}

__global__ __launch_bounds__(256) void HitTheMiddleModel_kernel(
        const float4* __restrict__ X4,
        const float* __restrict__ X,
        const float* __restrict__ W,
        const float* __restrict__ B,
        float4* __restrict__ O4,
        long long n4, long long nfloats) {
    long long q = (long long)blockIdx.x * blockDim.x + threadIdx.x;

    float Wv[9];
#pragma unroll
    for (int i = 0; i < 9; ++i) Wv[i] = W[i];
    float bv[3] = {B[0], B[1], B[2]};

    if (q >= n4) return;

    // Center + halos. Issue all three loads before any use (MLP).
    float4 C = X4[q];
    long long la = 4 * q - 2;                // even -> 8B aligned
    if (la < 0) la = 0;                      // q==0: unused (phase 0)
    long long ra = 4 * q + 4;                // w8,w9 = floats 4q+4,4q+5
    if (ra > nfloats - 2) ra = nfloats - 2;  // last q: unused (phase 2)
    float2 Lf = *(const float2*)(X + la);
    float2 Rf = *(const float2*)(X + ra);

    float w2 = Lf.x, w3 = Lf.y;
    float w4 = C.x, w5 = C.y, w6 = C.z, w7 = C.w;
    float w8 = Rf.x, w9 = Rf.y;

    int m = (int)((unsigned long long)q % 3ull);

    // Row A covers output float 4q (component m); row B is the next row.
    float a0 = sel3(m, w4, w3, w2);
    float a1 = sel3(m, w5, w4, w3);
    float a2 = sel3(m, w6, w5, w4);
    float b0 = sel3(m, w7, w6, w5);
    float b1 = sel3(m, w8, w7, w6);
    float b2 = sel3(m, w9, w8, w7);

    float pA, vA, rA, pB, vB, rB;
    sim_row(a0, a1, a2, Wv, bv, pA, vA, rA);
    sim_row(b0, b1, b2, Wv, bv, pB, vB, rB);

    float4 r;
    r.x = sel3(m, pA, vA, rA);
    r.y = sel3(m, vA, rA, pB);
    r.z = sel3(m, rA, pB, vB);
    r.w = sel3(m, pB, vB, rB);
    O4[q] = r;
}

// Scalar tail for nfloats % 4 != 0 (never launched for B = 2^23).
__global__ void HitTheMiddleModel_tail(
        const float* __restrict__ X, const float* __restrict__ W,
        const float* __restrict__ B, float* __restrict__ O,
        long long startFloat, long long nfloats) {
    long long g = startFloat + (long long)blockIdx.x * blockDim.x + threadIdx.x;
    if (g >= nfloats) return;
    float Wv[9];
    for (int i = 0; i < 9; ++i) Wv[i] = W[i];
    float bv[3] = {B[0], B[1], B[2]};
    long long row = g / 3;
    int c = (int)(g % 3);
    float x0 = X[3 * row], x1 = X[3 * row + 1], x2 = X[3 * row + 2];
    float p, v, rw;
    sim_row(x0, x1, x2, Wv, bv, p, v, rw);
    O[g] = (c == 0) ? p : (c == 1) ? v : rw;
}

extern "C" void kernel_launch(void* const* d_in, const int* in_sizes, int n_in,
                              void* d_out, int out_size, void* d_ws, size_t ws_size,
                              hipStream_t stream) {
    const float* x = (const float*)d_in[0];
    const float* W = (const float*)d_in[1];
    const float* b = (const float*)d_in[2];
    float* out = (float*)d_out;

    long long nfloats = (long long)in_sizes[0];   // 3 * rows
    long long n4 = nfloats / 4;                   // full float4s

    const int block = 256;
    long long grid = (n4 + block - 1) / block;
    HitTheMiddleModel_kernel<<<(int)grid, block, 0, stream>>>(
        (const float4*)x, x, W, b, (float4*)out, n4, nfloats);

    long long startFloat = 4 * n4;
    if (startFloat < nfloats) {
        long long tailN = nfloats - startFloat;
        int tgrid = (int)((tailN + 255) / 256);
        HitTheMiddleModel_tail<<<tgrid, 256, 0, stream>>>(
            x, W, b, out, startFloat, nfloats);
    }
}